// Round 2
// baseline (345.025 us; speedup 1.0000x reference)
//
#include <hip/hip_runtime.h>
#include <math.h>

#define NN 50000
#define NE 800000
#define ED 128
#define FD 512
#define QKV_BLOCKS (NN / 16)                // 3125
#define HIST_BLOCKS ((NE / 4 + 255) / 256)  // 782
#define SCAN_BLOCKS ((NN + 255) / 256)      // 196

typedef __attribute__((ext_vector_type(8))) short bf16x8;
typedef __attribute__((ext_vector_type(4))) float f32x4;

static __device__ __forceinline__ float wave_sum(float x) {
#pragma unroll
  for (int off = 32; off > 0; off >>= 1) x += __shfl_xor(x, off, 64);
  return x;
}

static __device__ __forceinline__ int wave_sum_i(int x) {
#pragma unroll
  for (int off = 32; off > 0; off >>= 1) x += __shfl_xor(x, off, 64);
  return x;
}

static __device__ __forceinline__ unsigned short f2bf(float f) {
  union { float f; unsigned u; } c; c.f = f;
  unsigned r = c.u + 0x7fffu + ((c.u >> 16) & 1u);
  return (unsigned short)(r >> 16);
}

static __device__ __forceinline__ float2 bfpair(unsigned u) {
  union { unsigned a; float f; } lo, hi;
  lo.a = u << 16; hi.a = u & 0xffff0000u;
  return make_float2(lo.f, hi.f);
}

// ---- one-time weight swizzle to fragment-major bf16 + deg zero ----
__global__ void k_prep(const float* __restrict__ Wqkv, const float* __restrict__ W1,
                       const float* __restrict__ W2, unsigned short* __restrict__ WqkvF,
                       unsigned short* __restrict__ W1F, unsigned short* __restrict__ W2F,
                       int* __restrict__ deg) {
  int idx = blockIdx.x * 256 + threadIdx.x;  // 65536 threads
  if (idx < NN) deg[idx] = 0;
  if (idx < 49152) {  // WqkvF: t<24, kb<4
    int j = idx & 7, l = (idx >> 3) & 63, kb = (idx >> 9) & 3, t = idx >> 11;
    int k = kb * 32 + (l >> 4) * 8 + j, n = t * 16 + (l & 15);
    WqkvF[idx] = f2bf(Wqkv[k * 384 + n]);
  }
  {  // W1F: t<32, kb<4
    int j = idx & 7, l = (idx >> 3) & 63, kb = (idx >> 9) & 3, t = idx >> 11;
    int k = kb * 32 + (l >> 4) * 8 + j, n = t * 16 + (l & 15);
    W1F[idx] = f2bf(W1[k * 512 + n]);
  }
  {  // W2F: t<8, kb<16
    int j = idx & 7, l = (idx >> 3) & 63, kb = (idx >> 9) & 15, t = idx >> 13;
    int k = kb * 32 + (l >> 4) * 8 + j, n = t * 16 + (l & 15);
    W2F[idx] = f2bf(W2[k * 128 + n]);
  }
}

// ---- fused: QKV GEMM + histogram; q pre-scaled by 128^-0.5, k/v interleaved ----
__global__ __launch_bounds__(256) void k_qkv_hist(
    const float* __restrict__ X, const unsigned short* __restrict__ WqkvF,
    const float* __restrict__ B, unsigned short* __restrict__ q,
    unsigned short* __restrict__ kv, const int* __restrict__ src,
    int* __restrict__ deg) {
  __shared__ unsigned short xs[16][136];
  const int tid = threadIdx.x;
  if (blockIdx.x >= QKV_BLOCKS) {
    const int e0 = ((blockIdx.x - QKV_BLOCKS) * 256 + tid) * 4;
    if (e0 < NE) {
      int4 s4 = *(const int4*)&src[e0];
      atomicAdd(&deg[s4.x], 1);
      atomicAdd(&deg[s4.y], 1);
      atomicAdd(&deg[s4.z], 1);
      atomicAdd(&deg[s4.w], 1);
    }
    return;
  }
  const int row0 = blockIdx.x * 16;
  for (int idx = tid; idx < 512; idx += 256) {
    int r = idx >> 5, c4 = (idx & 31) << 2;
    float4 val = *(const float4*)&X[(size_t)(row0 + r) * ED + c4];
    xs[r][c4] = f2bf(val.x); xs[r][c4 + 1] = f2bf(val.y);
    xs[r][c4 + 2] = f2bf(val.z); xs[r][c4 + 3] = f2bf(val.w);
  }
  __syncthreads();
  const int wv = tid >> 6, lane = tid & 63;
  const int ln = lane & 15, quad = lane >> 4;
  const int koff = quad * 8;
  bf16x8 a[4];
#pragma unroll
  for (int kb = 0; kb < 4; kb++) a[kb] = *(const bf16x8*)&xs[ln][kb * 32 + koff];
  for (int g = 0; g < 3; g++) {
    const int t0 = wv * 6 + g * 2;
    bf16x8 b[2][4];
#pragma unroll
    for (int j = 0; j < 2; j++)
#pragma unroll
      for (int kb = 0; kb < 4; kb++)
        b[j][kb] = *(const bf16x8*)&WqkvF[(size_t)(((t0 + j) * 4 + kb) * 64 + lane) * 8];
    f32x4 acc[2];
#pragma unroll
    for (int j = 0; j < 2; j++) acc[j] = (f32x4){0.f, 0.f, 0.f, 0.f};
#pragma unroll
    for (int kb = 0; kb < 4; kb++)
#pragma unroll
      for (int j = 0; j < 2; j++)
        acc[j] = __builtin_amdgcn_mfma_f32_16x16x32_bf16(a[kb], b[j][kb], acc[j], 0, 0, 0);
#pragma unroll
    for (int j = 0; j < 2; j++) {
      const int col = (t0 + j) * 16 + ln;
      const float bias = B[col];
      if (col < 128) {
#pragma unroll
        for (int r = 0; r < 4; r++)
          q[(size_t)(row0 + quad * 4 + r) * ED + col] =
              f2bf((acc[j][r] + bias) * 0.08838834764831845f);  // 128^-0.5
      } else {
#pragma unroll
        for (int r = 0; r < 4; r++)
          kv[(size_t)(row0 + quad * 4 + r) * 256 + (col - 128)] = f2bf(acc[j][r] + bias);
      }
    }
  }
}

// ---- two-phase parallel scan ----
__global__ __launch_bounds__(256) void k_scan1(const int* __restrict__ deg,
                                               int* __restrict__ blocksum) {
  const int tid = threadIdx.x;
  const int i = blockIdx.x * 256 + tid;
  int d = (i < NN) ? deg[i] : 0;
  int w = wave_sum_i(d);
  __shared__ int ws[4];
  if ((tid & 63) == 0) ws[tid >> 6] = w;
  __syncthreads();
  if (tid == 0) blocksum[blockIdx.x] = ws[0] + ws[1] + ws[2] + ws[3];
}

__global__ __launch_bounds__(256) void k_scan3(const int* __restrict__ deg,
                                               const int* __restrict__ blocksum,
                                               int* __restrict__ row_start,
                                               int* __restrict__ cursor) {
  __shared__ int bs[256];
  __shared__ int s[256];
  const int t = threadIdx.x;
  int bsv = (t < SCAN_BLOCKS) ? blocksum[t] : 0;
  bs[t] = bsv;
  __syncthreads();
  for (int off = 1; off < 256; off <<= 1) {
    int add = (t >= off) ? bs[t - off] : 0;
    __syncthreads();
    bs[t] += add;
    __syncthreads();
  }
  const int blockpre = (blockIdx.x > 0) ? bs[blockIdx.x - 1] : 0;
  const int i = blockIdx.x * 256 + t;
  int d = (i < NN) ? deg[i] : 0;
  s[t] = d;
  __syncthreads();
  for (int off = 1; off < 256; off <<= 1) {
    int add = (t >= off) ? s[t - off] : 0;
    __syncthreads();
    s[t] += add;
    __syncthreads();
  }
  const int pre = blockpre + s[t] - d;
  if (i < NN) {
    row_start[i] = pre;
    cursor[i] = pre;
  }
  if (i == NN) row_start[NN] = pre;
}

__global__ void k_scatter(const int* __restrict__ src, const int* __restrict__ dst,
                          int* __restrict__ cursor, int* __restrict__ colidx) {
  const int e0 = (blockIdx.x * 256 + threadIdx.x) * 4;
  if (e0 < NE) {
    int4 s4 = *(const int4*)&src[e0];
    int4 d4 = *(const int4*)&dst[e0];
    colidx[atomicAdd(&cursor[s4.x], 1)] = d4.x;
    colidx[atomicAdd(&cursor[s4.y], 1)] = d4.y;
    colidx[atomicAdd(&cursor[s4.z], 1)] = d4.z;
    colidx[atomicAdd(&cursor[s4.w], 1)] = d4.w;
  }
}

// ---- attention: each wave owns TWO nodes; chunks for both nodes are issued
// back-to-back so a wave keeps up to 16 independent uint4 gathers in flight
// (2x the single-node version) — attacks the latency-bound signature
// (VALUBusy 56%, HBM 44%, no pipe saturated). K/V interleaved per node:
// kv[c*256 + d] = K, kv[c*256 + 128 + d] = V → one contiguous 512B region/edge.
template <bool DA, bool DB, bool FULL>
static __device__ __forceinline__ void attn2(
    int baseA, int cA, int baseB, int cB, int grp, int gl, int lane,
    const float* qa, const float* qb, const unsigned short* __restrict__ kv,
    const int* __restrict__ colidx, float& lA, float& lB, float* axA, float* axB) {
  int col = 0;
  const int idx = lane & 15;
  if (DA && lane < 16) {
    if (FULL || idx < cA) col = colidx[baseA + idx];
  }
  if (DB && lane >= 16 && lane < 32) {
    if (FULL || idx < cB) col = colidx[baseB + idx];
  }
#pragma unroll
  for (int it = 0; it < 4; it++) {
    const int t = it * 4 + grp;
    uint4 kwA, vwA, kwB, vwB;
    bool actA = false, actB = false;
    if (DA) {
      actA = FULL || t < cA;
      // inactive lanes re-load slot 0's row (L1/L2 hit, no extra HBM)
      const int cc = __shfl(col, actA ? t : 0, 64);
      kwA = *(const uint4*)&kv[(size_t)cc * 256 + gl * 8];
      vwA = *(const uint4*)&kv[(size_t)cc * 256 + 128 + gl * 8];
    }
    if (DB) {
      actB = FULL || t < cB;
      const int cc = __shfl(col, 16 + (actB ? t : 0), 64);
      kwB = *(const uint4*)&kv[(size_t)cc * 256 + gl * 8];
      vwB = *(const uint4*)&kv[(size_t)cc * 256 + 128 + gl * 8];
    }
    if (DA) {
      float2 k0 = bfpair(kwA.x), k1 = bfpair(kwA.y), k2 = bfpair(kwA.z), k3 = bfpair(kwA.w);
      float dot = qa[0] * k0.x + qa[1] * k0.y + qa[2] * k1.x + qa[3] * k1.y +
                  qa[4] * k2.x + qa[5] * k2.y + qa[6] * k3.x + qa[7] * k3.y;
      dot += __shfl_xor(dot, 1, 64);
      dot += __shfl_xor(dot, 2, 64);
      dot += __shfl_xor(dot, 4, 64);
      dot += __shfl_xor(dot, 8, 64);
      const float e = actA ? __expf(dot) : 0.f;  // q pre-scaled by 128^-0.5
      lA += e;
      float2 v0 = bfpair(vwA.x), v1 = bfpair(vwA.y), v2 = bfpair(vwA.z), v3 = bfpair(vwA.w);
      axA[0] = fmaf(e, v0.x, axA[0]); axA[1] = fmaf(e, v0.y, axA[1]);
      axA[2] = fmaf(e, v1.x, axA[2]); axA[3] = fmaf(e, v1.y, axA[3]);
      axA[4] = fmaf(e, v2.x, axA[4]); axA[5] = fmaf(e, v2.y, axA[5]);
      axA[6] = fmaf(e, v3.x, axA[6]); axA[7] = fmaf(e, v3.y, axA[7]);
    }
    if (DB) {
      float2 k0 = bfpair(kwB.x), k1 = bfpair(kwB.y), k2 = bfpair(kwB.z), k3 = bfpair(kwB.w);
      float dot = qb[0] * k0.x + qb[1] * k0.y + qb[2] * k1.x + qb[3] * k1.y +
                  qb[4] * k2.x + qb[5] * k2.y + qb[6] * k3.x + qb[7] * k3.y;
      dot += __shfl_xor(dot, 1, 64);
      dot += __shfl_xor(dot, 2, 64);
      dot += __shfl_xor(dot, 4, 64);
      dot += __shfl_xor(dot, 8, 64);
      const float e = actB ? __expf(dot) : 0.f;
      lB += e;
      float2 v0 = bfpair(vwB.x), v1 = bfpair(vwB.y), v2 = bfpair(vwB.z), v3 = bfpair(vwB.w);
      axB[0] = fmaf(e, v0.x, axB[0]); axB[1] = fmaf(e, v0.y, axB[1]);
      axB[2] = fmaf(e, v1.x, axB[2]); axB[3] = fmaf(e, v1.y, axB[3]);
      axB[4] = fmaf(e, v2.x, axB[4]); axB[5] = fmaf(e, v2.y, axB[5]);
      axB[6] = fmaf(e, v3.x, axB[6]); axB[7] = fmaf(e, v3.y, axB[7]);
    }
  }
}

static __device__ __forceinline__ void ln_store(
    int node, int grp, int gl, float l, int cnt, const float* ax,
    const float* __restrict__ x, const float* __restrict__ g1,
    const float* __restrict__ be1, float* __restrict__ out) {
  const float inv = (cnt > 0) ? 1.0f / l : 0.f;
  const int d0 = gl * 8 + grp * 2;
  float sx = (grp == 0) ? ax[0] : (grp == 1) ? ax[2] : (grp == 2) ? ax[4] : ax[6];
  float sy = (grp == 0) ? ax[1] : (grp == 1) ? ax[3] : (grp == 2) ? ax[5] : ax[7];
  float2 xv = *(const float2*)&x[(size_t)node * ED + d0];
  float vx = xv.x + sx * inv;
  float vy = xv.y + sy * inv;
  float mean = wave_sum(vx + vy) * (1.f / ED);
  float dx = vx - mean, dy = vy - mean;
  float var = wave_sum(dx * dx + dy * dy) * (1.f / ED);
  float rstd = rsqrtf(var + 1e-5f);
  float2 gg = *(const float2*)&g1[d0];
  float2 bb = *(const float2*)&be1[d0];
  *(float2*)&out[(size_t)node * ED + d0] =
      make_float2(dx * rstd * gg.x + bb.x, dy * rstd * gg.y + bb.y);
}

__global__ __launch_bounds__(256) void k_attn_ln1(
    const unsigned short* __restrict__ q, const unsigned short* __restrict__ kv,
    const float* __restrict__ x, const int* __restrict__ row_start,
    const int* __restrict__ colidx, const float* __restrict__ g1,
    const float* __restrict__ be1, float* __restrict__ out) {
  const int wv = threadIdx.x >> 6;
  const int lane = threadIdx.x & 63;
  const int grp = lane >> 4, gl = lane & 15;
  const int nodeA = blockIdx.x * 8 + wv * 2;  // NN % 8 == 0

  float qa[8], qb[8];
  {
    uint4 qw = *(const uint4*)&q[(size_t)nodeA * ED + gl * 8];
    float2 p0 = bfpair(qw.x), p1 = bfpair(qw.y), p2 = bfpair(qw.z), p3 = bfpair(qw.w);
    qa[0] = p0.x; qa[1] = p0.y; qa[2] = p1.x; qa[3] = p1.y;
    qa[4] = p2.x; qa[5] = p2.y; qa[6] = p3.x; qa[7] = p3.y;
  }
  {
    uint4 qw = *(const uint4*)&q[(size_t)(nodeA + 1) * ED + gl * 8];
    float2 p0 = bfpair(qw.x), p1 = bfpair(qw.y), p2 = bfpair(qw.z), p3 = bfpair(qw.w);
    qb[0] = p0.x; qb[1] = p0.y; qb[2] = p1.x; qb[3] = p1.y;
    qb[4] = p2.x; qb[5] = p2.y; qb[6] = p3.x; qb[7] = p3.y;
  }
  const int rA0 = row_start[nodeA];
  const int rA1 = row_start[nodeA + 1];
  const int rB1 = row_start[nodeA + 2];
  int baseA = rA0, baseB = rA1;
  float lA = 0.f, lB = 0.f;
  float axA[8] = {0.f, 0.f, 0.f, 0.f, 0.f, 0.f, 0.f, 0.f};
  float axB[8] = {0.f, 0.f, 0.f, 0.f, 0.f, 0.f, 0.f, 0.f};

  const int fA = (rA1 - rA0) >> 4, fB = (rB1 - rA1) >> 4;
  const int both = fA < fB ? fA : fB;
  for (int i = 0; i < both; i++) {
    attn2<true, true, true>(baseA, 16, baseB, 16, grp, gl, lane, qa, qb, kv,
                            colidx, lA, lB, axA, axB);
    baseA += 16; baseB += 16;
  }
  for (int i = both; i < fA; i++) {
    attn2<true, false, true>(baseA, 16, 0, 0, grp, gl, lane, qa, qb, kv,
                             colidx, lA, lB, axA, axB);
    baseA += 16;
  }
  for (int i = both; i < fB; i++) {
    attn2<false, true, true>(0, 0, baseB, 16, grp, gl, lane, qa, qb, kv,
                             colidx, lA, lB, axA, axB);
    baseB += 16;
  }
  const int tA = rA1 - baseA, tB = rB1 - baseB;
  if (tA && tB)
    attn2<true, true, false>(baseA, tA, baseB, tB, grp, gl, lane, qa, qb, kv,
                             colidx, lA, lB, axA, axB);
  else if (tA)
    attn2<true, false, false>(baseA, tA, 0, 0, grp, gl, lane, qa, qb, kv,
                              colidx, lA, lB, axA, axB);
  else if (tB)
    attn2<false, true, false>(0, 0, baseB, tB, grp, gl, lane, qa, qb, kv,
                              colidx, lA, lB, axA, axB);

  // cross-group reduction: groups hold disjoint edge subsets
#pragma unroll
  for (int j = 0; j < 8; j++) {
    axA[j] += __shfl_xor(axA[j], 16, 64);
    axA[j] += __shfl_xor(axA[j], 32, 64);
    axB[j] += __shfl_xor(axB[j], 16, 64);
    axB[j] += __shfl_xor(axB[j], 32, 64);
  }
  lA += __shfl_xor(lA, 16, 64);
  lA += __shfl_xor(lA, 32, 64);
  lB += __shfl_xor(lB, 16, 64);
  lB += __shfl_xor(lB, 32, 64);

  ln_store(nodeA, grp, gl, lA, rA1 - rA0, axA, x, g1, be1, out);
  ln_store(nodeA + 1, grp, gl, lB, rB1 - rA1, axB, x, g1, be1, out);
}

// ---- FFN via MFMA: 16 rows/block + residual + LN2, in-place on out ----
__global__ __launch_bounds__(256) void k_ffn_ln2(
    const float* __restrict__ x1, const unsigned short* __restrict__ W1F,
    const float* __restrict__ b1, const unsigned short* __restrict__ W2F,
    const float* __restrict__ b2, const float* __restrict__ g2,
    const float* __restrict__ be2, float* __restrict__ out) {
  __shared__ unsigned short xs[16][136];
  __shared__ unsigned short hs[16][520];  // later aliased ys f32[16][132]
  float* ys = (float*)&hs[0][0];
  const int row0 = blockIdx.x * 16;
  const int tid = threadIdx.x;
  for (int idx = tid; idx < 512; idx += 256) {
    int r = idx >> 5, c4 = (idx & 31) << 2;
    float4 val = *(const float4*)&x1[(size_t)(row0 + r) * ED + c4];
    xs[r][c4] = f2bf(val.x); xs[r][c4 + 1] = f2bf(val.y);
    xs[r][c4 + 2] = f2bf(val.z); xs[r][c4 + 3] = f2bf(val.w);
  }
  __syncthreads();
  const int wv = tid >> 6, lane = tid & 63;
  const int ln = lane & 15, quad = lane >> 4;
  const int koff = quad * 8;
  bf16x8 a1[4];
#pragma unroll
  for (int kb = 0; kb < 4; kb++) a1[kb] = *(const bf16x8*)&xs[ln][kb * 32 + koff];
  for (int g = 0; g < 4; g++) {
    const int t0 = wv * 8 + g * 2;
    bf16x8 b[2][4];
#pragma unroll
    for (int j = 0; j < 2; j++)
#pragma unroll
      for (int kb = 0; kb < 4; kb++)
        b[j][kb] = *(const bf16x8*)&W1F[(size_t)(((t0 + j) * 4 + kb) * 64 + lane) * 8];
    f32x4 acc[2];
#pragma unroll
    for (int j = 0; j < 2; j++) acc[j] = (f32x4){0.f, 0.f, 0.f, 0.f};
#pragma unroll
    for (int kb = 0; kb < 4; kb++)
#pragma unroll
      for (int j = 0; j < 2; j++)
        acc[j] = __builtin_amdgcn_mfma_f32_16x16x32_bf16(a1[kb], b[j][kb], acc[j], 0, 0, 0);
#pragma unroll
    for (int j = 0; j < 2; j++) {
      const int col = (t0 + j) * 16 + ln;
      const float bias = b1[col];
#pragma unroll
      for (int r = 0; r < 4; r++)
        hs[quad * 4 + r][col] = f2bf(fmaxf(acc[j][r] + bias, 0.f));
    }
  }
  __syncthreads();
  f32x4 acc2[2];
  acc2[0] = (f32x4){0.f, 0.f, 0.f, 0.f};
  acc2[1] = (f32x4){0.f, 0.f, 0.f, 0.f};
  const int nt0 = wv * 2;
  for (int kg = 0; kg < 4; kg++) {
    bf16x8 a[4];
#pragma unroll
    for (int kk = 0; kk < 4; kk++)
      a[kk] = *(const bf16x8*)&hs[ln][(kg * 4 + kk) * 32 + koff];
    bf16x8 b[2][4];
#pragma unroll
    for (int nt = 0; nt < 2; nt++)
#pragma unroll
      for (int kk = 0; kk < 4; kk++)
        b[nt][kk] = *(const bf16x8*)&W2F[(size_t)(((nt0 + nt) * 16 + kg * 4 + kk) * 64 + lane) * 8];
#pragma unroll
    for (int kk = 0; kk < 4; kk++)
#pragma unroll
      for (int nt = 0; nt < 2; nt++)
        acc2[nt] = __builtin_amdgcn_mfma_f32_16x16x32_bf16(a[kk], b[nt][kk], acc2[nt], 0, 0, 0);
  }
  __syncthreads();
#pragma unroll
  for (int nt = 0; nt < 2; nt++) {
    const int col = (nt0 + nt) * 16 + ln;
    const float bias = b2[col];
#pragma unroll
    for (int r = 0; r < 4; r++)
      ys[(quad * 4 + r) * 132 + col] = acc2[nt][r] + bias;
  }
  __syncthreads();
  float2 gg = *(const float2*)&g2[2 * lane];
  float2 bbe = *(const float2*)&be2[2 * lane];
#pragma unroll
  for (int rr = 0; rr < 4; rr++) {
    const int r = wv * 4 + rr;
    const int row = row0 + r;
    float2 xr = *(const float2*)&out[(size_t)row * ED + 2 * lane];
    float vx = ys[r * 132 + 2 * lane] + xr.x;
    float vy = ys[r * 132 + 2 * lane + 1] + xr.y;
    float mean = wave_sum(vx + vy) * (1.f / ED);
    float dx = vx - mean, dy = vy - mean;
    float var = wave_sum(dx * dx + dy * dy) * (1.f / ED);
    float rstd = rsqrtf(var + 1e-5f);
    float2 o = make_float2(dx * rstd * gg.x + bbe.x, dy * rstd * gg.y + bbe.y);
    *(float2*)&out[(size_t)row * ED + 2 * lane] = o;
  }
}

extern "C" void kernel_launch(void* const* d_in, const int* in_sizes, int n_in,
                              void* d_out, int out_size, void* d_ws, size_t ws_size,
                              hipStream_t stream) {
  const float* x = (const float*)d_in[0];
  const int* ei = (const int*)d_in[1];
  const float* W_qkv = (const float*)d_in[2];
  const float* b_qkv = (const float*)d_in[3];
  const float* W1 = (const float*)d_in[4];
  const float* b1 = (const float*)d_in[5];
  const float* W2 = (const float*)d_in[6];
  const float* b2 = (const float*)d_in[7];
  const float* g1 = (const float*)d_in[8];
  const float* be1 = (const float*)d_in[9];
  const float* g2 = (const float*)d_in[10];
  const float* be2 = (const float*)d_in[11];
  float* out = (float*)d_out;

  char* ws = (char*)d_ws;
  size_t off = 0;
  auto alloc = [&](size_t bytes) -> char* {
    char* p = ws + off;
    off = (off + bytes + 255) & ~(size_t)255;
    return p;
  };
  unsigned short* q = (unsigned short*)alloc(2 * (size_t)NN * ED);
  unsigned short* kv = (unsigned short*)alloc(2 * (size_t)NN * 256);
  unsigned short* WqkvF = (unsigned short*)alloc(2 * 24 * 4 * 64 * 8);
  unsigned short* W1F = (unsigned short*)alloc(2 * 32 * 4 * 64 * 8);
  unsigned short* W2F = (unsigned short*)alloc(2 * 8 * 16 * 64 * 8);
  int* deg = (int*)alloc(sizeof(int) * NN);
  int* cursor = (int*)alloc(sizeof(int) * NN);
  int* row_start = (int*)alloc(sizeof(int) * (NN + 1));
  int* colidx = (int*)alloc(sizeof(int) * NE);
  int* blocksum = (int*)alloc(sizeof(int) * SCAN_BLOCKS);

  k_prep<<<256, 256, 0, stream>>>(W_qkv, W1, W2, WqkvF, W1F, W2F, deg);
  k_qkv_hist<<<QKV_BLOCKS + HIST_BLOCKS, 256, 0, stream>>>(x, WqkvF, b_qkv, q, kv, ei, deg);
  k_scan1<<<SCAN_BLOCKS, 256, 0, stream>>>(deg, blocksum);
  k_scan3<<<SCAN_BLOCKS, 256, 0, stream>>>(deg, blocksum, row_start, cursor);
  k_scatter<<<HIST_BLOCKS, 256, 0, stream>>>(ei, ei + NE, cursor, colidx);
  k_attn_ln1<<<NN / 8, 256, 0, stream>>>(q, kv, x, row_start, colidx, g1, be1, out);
  k_ffn_ln2<<<NN / 16, 256, 0, stream>>>(out, W1F, b1, W2F, b2, g2, be2, out);
}

// Round 3
// 299.640 us; speedup vs baseline: 1.1515x; 1.1515x over previous
//
#include <hip/hip_runtime.h>
#include <math.h>

#define NN 50000
#define NE 800000
#define ED 128
#define FD 512
#define QKV_BLOCKS (NN / 16)                // 3125
#define HIST_BLOCKS ((NE / 4 + 255) / 256)  // 782
#define SCAN_BLOCKS ((NN + 255) / 256)      // 196

typedef __attribute__((ext_vector_type(8))) short bf16x8;
typedef __attribute__((ext_vector_type(4))) float f32x4;

static __device__ __forceinline__ float wave_sum(float x) {
#pragma unroll
  for (int off = 32; off > 0; off >>= 1) x += __shfl_xor(x, off, 64);
  return x;
}

static __device__ __forceinline__ int wave_sum_i(int x) {
#pragma unroll
  for (int off = 32; off > 0; off >>= 1) x += __shfl_xor(x, off, 64);
  return x;
}

static __device__ __forceinline__ unsigned short f2bf(float f) {
  union { float f; unsigned u; } c; c.f = f;
  unsigned r = c.u + 0x7fffu + ((c.u >> 16) & 1u);
  return (unsigned short)(r >> 16);
}

static __device__ __forceinline__ float2 bfpair(unsigned u) {
  union { unsigned a; float f; } lo, hi;
  lo.a = u << 16; hi.a = u & 0xffff0000u;
  return make_float2(lo.f, hi.f);
}

// ---- one-time weight swizzle to fragment-major bf16 + deg zero ----
__global__ void k_prep(const float* __restrict__ Wqkv, const float* __restrict__ W1,
                       const float* __restrict__ W2, unsigned short* __restrict__ WqkvF,
                       unsigned short* __restrict__ W1F, unsigned short* __restrict__ W2F,
                       int* __restrict__ deg) {
  int idx = blockIdx.x * 256 + threadIdx.x;  // 65536 threads
  if (idx < NN) deg[idx] = 0;
  if (idx < 49152) {  // WqkvF: t<24, kb<4
    int j = idx & 7, l = (idx >> 3) & 63, kb = (idx >> 9) & 3, t = idx >> 11;
    int k = kb * 32 + (l >> 4) * 8 + j, n = t * 16 + (l & 15);
    WqkvF[idx] = f2bf(Wqkv[k * 384 + n]);
  }
  {  // W1F: t<32, kb<4
    int j = idx & 7, l = (idx >> 3) & 63, kb = (idx >> 9) & 3, t = idx >> 11;
    int k = kb * 32 + (l >> 4) * 8 + j, n = t * 16 + (l & 15);
    W1F[idx] = f2bf(W1[k * 512 + n]);
  }
  {  // W2F: t<8, kb<16
    int j = idx & 7, l = (idx >> 3) & 63, kb = (idx >> 9) & 15, t = idx >> 13;
    int k = kb * 32 + (l >> 4) * 8 + j, n = t * 16 + (l & 15);
    W2F[idx] = f2bf(W2[k * 128 + n]);
  }
}

// ---- fused: QKV GEMM + histogram; q pre-scaled by 128^-0.5 ----
__global__ __launch_bounds__(256) void k_qkv_hist(
    const float* __restrict__ X, const unsigned short* __restrict__ WqkvF,
    const float* __restrict__ B, unsigned short* __restrict__ q,
    unsigned short* __restrict__ k, unsigned short* __restrict__ v,
    const int* __restrict__ src, int* __restrict__ deg) {
  __shared__ unsigned short xs[16][136];
  const int tid = threadIdx.x;
  if (blockIdx.x >= QKV_BLOCKS) {
    const int e0 = ((blockIdx.x - QKV_BLOCKS) * 256 + tid) * 4;
    if (e0 < NE) {
      int4 s4 = *(const int4*)&src[e0];
      atomicAdd(&deg[s4.x], 1);
      atomicAdd(&deg[s4.y], 1);
      atomicAdd(&deg[s4.z], 1);
      atomicAdd(&deg[s4.w], 1);
    }
    return;
  }
  const int row0 = blockIdx.x * 16;
  for (int idx = tid; idx < 512; idx += 256) {
    int r = idx >> 5, c4 = (idx & 31) << 2;
    float4 val = *(const float4*)&X[(size_t)(row0 + r) * ED + c4];
    xs[r][c4] = f2bf(val.x); xs[r][c4 + 1] = f2bf(val.y);
    xs[r][c4 + 2] = f2bf(val.z); xs[r][c4 + 3] = f2bf(val.w);
  }
  __syncthreads();
  const int wv = tid >> 6, lane = tid & 63;
  const int ln = lane & 15, quad = lane >> 4;
  const int koff = quad * 8;
  bf16x8 a[4];
#pragma unroll
  for (int kb = 0; kb < 4; kb++) a[kb] = *(const bf16x8*)&xs[ln][kb * 32 + koff];
  for (int g = 0; g < 3; g++) {
    const int t0 = wv * 6 + g * 2;
    bf16x8 b[2][4];
#pragma unroll
    for (int j = 0; j < 2; j++)
#pragma unroll
      for (int kb = 0; kb < 4; kb++)
        b[j][kb] = *(const bf16x8*)&WqkvF[(size_t)(((t0 + j) * 4 + kb) * 64 + lane) * 8];
    f32x4 acc[2];
#pragma unroll
    for (int j = 0; j < 2; j++) acc[j] = (f32x4){0.f, 0.f, 0.f, 0.f};
#pragma unroll
    for (int kb = 0; kb < 4; kb++)
#pragma unroll
      for (int j = 0; j < 2; j++)
        acc[j] = __builtin_amdgcn_mfma_f32_16x16x32_bf16(a[kb], b[j][kb], acc[j], 0, 0, 0);
#pragma unroll
    for (int j = 0; j < 2; j++) {
      const int col = (t0 + j) * 16 + ln;
      const float bias = B[col];
      if (col < 128) {
#pragma unroll
        for (int r = 0; r < 4; r++)
          q[(size_t)(row0 + quad * 4 + r) * ED + col] =
              f2bf((acc[j][r] + bias) * 0.08838834764831845f);  // 128^-0.5
      } else {
        unsigned short* dst = (col < 256) ? k : v;
        const int c = col & 127;
#pragma unroll
        for (int r = 0; r < 4; r++)
          dst[(size_t)(row0 + quad * 4 + r) * ED + c] = f2bf(acc[j][r] + bias);
      }
    }
  }
}

// ---- two-phase parallel scan ----
__global__ __launch_bounds__(256) void k_scan1(const int* __restrict__ deg,
                                               int* __restrict__ blocksum) {
  const int tid = threadIdx.x;
  const int i = blockIdx.x * 256 + tid;
  int d = (i < NN) ? deg[i] : 0;
  int w = wave_sum_i(d);
  __shared__ int ws[4];
  if ((tid & 63) == 0) ws[tid >> 6] = w;
  __syncthreads();
  if (tid == 0) blocksum[blockIdx.x] = ws[0] + ws[1] + ws[2] + ws[3];
}

__global__ __launch_bounds__(256) void k_scan3(const int* __restrict__ deg,
                                               const int* __restrict__ blocksum,
                                               int* __restrict__ row_start,
                                               int* __restrict__ cursor) {
  __shared__ int bs[256];
  __shared__ int s[256];
  const int t = threadIdx.x;
  int bsv = (t < SCAN_BLOCKS) ? blocksum[t] : 0;
  bs[t] = bsv;
  __syncthreads();
  for (int off = 1; off < 256; off <<= 1) {
    int add = (t >= off) ? bs[t - off] : 0;
    __syncthreads();
    bs[t] += add;
    __syncthreads();
  }
  const int blockpre = (blockIdx.x > 0) ? bs[blockIdx.x - 1] : 0;
  const int i = blockIdx.x * 256 + t;
  int d = (i < NN) ? deg[i] : 0;
  s[t] = d;
  __syncthreads();
  for (int off = 1; off < 256; off <<= 1) {
    int add = (t >= off) ? s[t - off] : 0;
    __syncthreads();
    s[t] += add;
    __syncthreads();
  }
  const int pre = blockpre + s[t] - d;
  if (i < NN) {
    row_start[i] = pre;
    cursor[i] = pre;
  }
  if (i == NN) row_start[NN] = pre;
}

__global__ void k_scatter(const int* __restrict__ src, const int* __restrict__ dst,
                          int* __restrict__ cursor, int* __restrict__ colidx) {
  const int e0 = (blockIdx.x * 256 + threadIdx.x) * 4;
  if (e0 < NE) {
    int4 s4 = *(const int4*)&src[e0];
    int4 d4 = *(const int4*)&dst[e0];
    colidx[atomicAdd(&cursor[s4.x], 1)] = d4.x;
    colidx[atomicAdd(&cursor[s4.y], 1)] = d4.y;
    colidx[atomicAdd(&cursor[s4.z], 1)] = d4.z;
    colidx[atomicAdd(&cursor[s4.w], 1)] = d4.w;
  }
}

// ---- attention chunk with BATCHED gathers: compute all 4 broadcast columns,
// issue all 8 uint4 loads back-to-back (32 VGPRs of in-flight data, 4x the
// serialized baseline), then consume. Attacks the latency-bound signature
// (VALUBusy 56%, HBM 44%, occupancy 50%, nothing saturated) without the
// register blow-up that made round-1's 2-node version spill to scratch
// (WRITE_SIZE 25->257 MB).
template <bool FULL>
static __device__ __forceinline__ void attn_chunk(
    int base, int cnt, int grp, int gl, int lane, const float* qf,
    const unsigned short* __restrict__ k, const unsigned short* __restrict__ v,
    const int* __restrict__ colidx, float& l, float* ax) {
  const int C = FULL ? 16 : cnt;
  int colreg = 0;
  if (lane < C) colreg = colidx[base + lane];
  int cc[4];
  bool act[4];
#pragma unroll
  for (int it = 0; it < 4; it++) {
    const int t = it * 4 + grp;
    act[it] = FULL || t < C;
    // inactive lanes re-load slot 0's row (valid, L1/L2-hit, masked by e=0)
    cc[it] = __shfl(colreg, act[it] ? t : 0, 64);
  }
  uint4 kw[4], vw[4];
#pragma unroll
  for (int it = 0; it < 4; it++) kw[it] = *(const uint4*)&k[(size_t)cc[it] * ED + gl * 8];
#pragma unroll
  for (int it = 0; it < 4; it++) vw[it] = *(const uint4*)&v[(size_t)cc[it] * ED + gl * 8];
#pragma unroll
  for (int it = 0; it < 4; it++) {
    float2 k0 = bfpair(kw[it].x), k1 = bfpair(kw[it].y), k2 = bfpair(kw[it].z), k3 = bfpair(kw[it].w);
    float dot = qf[0] * k0.x + qf[1] * k0.y + qf[2] * k1.x + qf[3] * k1.y +
                qf[4] * k2.x + qf[5] * k2.y + qf[6] * k3.x + qf[7] * k3.y;
    dot += __shfl_xor(dot, 1, 64);
    dot += __shfl_xor(dot, 2, 64);
    dot += __shfl_xor(dot, 4, 64);
    dot += __shfl_xor(dot, 8, 64);
    const float e = act[it] ? __expf(dot) : 0.f;  // q pre-scaled by 128^-0.5
    l += e;
    float2 v0 = bfpair(vw[it].x), v1 = bfpair(vw[it].y), v2 = bfpair(vw[it].z), v3 = bfpair(vw[it].w);
    ax[0] = fmaf(e, v0.x, ax[0]); ax[1] = fmaf(e, v0.y, ax[1]);
    ax[2] = fmaf(e, v1.x, ax[2]); ax[3] = fmaf(e, v1.y, ax[3]);
    ax[4] = fmaf(e, v2.x, ax[4]); ax[5] = fmaf(e, v2.y, ax[5]);
    ax[6] = fmaf(e, v3.x, ax[6]); ax[7] = fmaf(e, v3.y, ax[7]);
  }
}

__global__ __launch_bounds__(256) void k_attn_ln1(
    const unsigned short* __restrict__ q, const unsigned short* __restrict__ k,
    const unsigned short* __restrict__ v, const float* __restrict__ x,
    const int* __restrict__ row_start, const int* __restrict__ colidx,
    const float* __restrict__ g1, const float* __restrict__ be1,
    float* __restrict__ out) {
  const int wv = threadIdx.x >> 6;
  const int lane = threadIdx.x & 63;
  const int grp = lane >> 4, gl = lane & 15;
  const int node = blockIdx.x * 4 + wv;  // NN % 4 == 0

  float qf[8];
  {
    uint4 qw = *(const uint4*)&q[(size_t)node * ED + gl * 8];
    float2 p0 = bfpair(qw.x), p1 = bfpair(qw.y), p2 = bfpair(qw.z), p3 = bfpair(qw.w);
    qf[0] = p0.x; qf[1] = p0.y; qf[2] = p1.x; qf[3] = p1.y;
    qf[4] = p2.x; qf[5] = p2.y; qf[6] = p3.x; qf[7] = p3.y;
  }
  const int r0 = row_start[node], r1 = row_start[node + 1];
  float l = 0.f;
  float ax[8] = {0.f, 0.f, 0.f, 0.f, 0.f, 0.f, 0.f, 0.f};
  int base = r0;
  for (; base + 16 <= r1; base += 16)
    attn_chunk<true>(base, 16, grp, gl, lane, qf, k, v, colidx, l, ax);
  if (base < r1)
    attn_chunk<false>(base, r1 - base, grp, gl, lane, qf, k, v, colidx, l, ax);

  // cross-group reduction: groups hold disjoint edge subsets
#pragma unroll
  for (int j = 0; j < 8; j++) {
    ax[j] += __shfl_xor(ax[j], 16, 64);
    ax[j] += __shfl_xor(ax[j], 32, 64);
  }
  l += __shfl_xor(l, 16, 64);
  l += __shfl_xor(l, 32, 64);

  const float inv = (r1 > r0) ? 1.0f / l : 0.f;
  // this lane outputs dims d0, d0+1 (dims partitioned uniquely over 64 lanes)
  const int d0 = gl * 8 + grp * 2;
  float sx = (grp == 0) ? ax[0] : (grp == 1) ? ax[2] : (grp == 2) ? ax[4] : ax[6];
  float sy = (grp == 0) ? ax[1] : (grp == 1) ? ax[3] : (grp == 2) ? ax[5] : ax[7];
  float2 xv = *(const float2*)&x[(size_t)node * ED + d0];
  float vx = xv.x + sx * inv;
  float vy = xv.y + sy * inv;
  float mean = wave_sum(vx + vy) * (1.f / ED);
  float dx = vx - mean, dy = vy - mean;
  float var = wave_sum(dx * dx + dy * dy) * (1.f / ED);
  float rstd = rsqrtf(var + 1e-5f);
  float2 gg = *(const float2*)&g1[d0];
  float2 bb = *(const float2*)&be1[d0];
  float2 o = make_float2(dx * rstd * gg.x + bb.x, dy * rstd * gg.y + bb.y);
  *(float2*)&out[(size_t)node * ED + d0] = o;
}

// ---- FFN via MFMA: 16 rows/block + residual + LN2, in-place on out ----
__global__ __launch_bounds__(256) void k_ffn_ln2(
    const float* __restrict__ x1, const unsigned short* __restrict__ W1F,
    const float* __restrict__ b1, const unsigned short* __restrict__ W2F,
    const float* __restrict__ b2, const float* __restrict__ g2,
    const float* __restrict__ be2, float* __restrict__ out) {
  __shared__ unsigned short xs[16][136];
  __shared__ unsigned short hs[16][520];  // later aliased ys f32[16][132]
  float* ys = (float*)&hs[0][0];
  const int row0 = blockIdx.x * 16;
  const int tid = threadIdx.x;
  for (int idx = tid; idx < 512; idx += 256) {
    int r = idx >> 5, c4 = (idx & 31) << 2;
    float4 val = *(const float4*)&x1[(size_t)(row0 + r) * ED + c4];
    xs[r][c4] = f2bf(val.x); xs[r][c4 + 1] = f2bf(val.y);
    xs[r][c4 + 2] = f2bf(val.z); xs[r][c4 + 3] = f2bf(val.w);
  }
  __syncthreads();
  const int wv = tid >> 6, lane = tid & 63;
  const int ln = lane & 15, quad = lane >> 4;
  const int koff = quad * 8;
  bf16x8 a1[4];
#pragma unroll
  for (int kb = 0; kb < 4; kb++) a1[kb] = *(const bf16x8*)&xs[ln][kb * 32 + koff];
  for (int g = 0; g < 4; g++) {
    const int t0 = wv * 8 + g * 2;
    bf16x8 b[2][4];
#pragma unroll
    for (int j = 0; j < 2; j++)
#pragma unroll
      for (int kb = 0; kb < 4; kb++)
        b[j][kb] = *(const bf16x8*)&W1F[(size_t)(((t0 + j) * 4 + kb) * 64 + lane) * 8];
    f32x4 acc[2];
#pragma unroll
    for (int j = 0; j < 2; j++) acc[j] = (f32x4){0.f, 0.f, 0.f, 0.f};
#pragma unroll
    for (int kb = 0; kb < 4; kb++)
#pragma unroll
      for (int j = 0; j < 2; j++)
        acc[j] = __builtin_amdgcn_mfma_f32_16x16x32_bf16(a1[kb], b[j][kb], acc[j], 0, 0, 0);
#pragma unroll
    for (int j = 0; j < 2; j++) {
      const int col = (t0 + j) * 16 + ln;
      const float bias = b1[col];
#pragma unroll
      for (int r = 0; r < 4; r++)
        hs[quad * 4 + r][col] = f2bf(fmaxf(acc[j][r] + bias, 0.f));
    }
  }
  __syncthreads();
  f32x4 acc2[2];
  acc2[0] = (f32x4){0.f, 0.f, 0.f, 0.f};
  acc2[1] = (f32x4){0.f, 0.f, 0.f, 0.f};
  const int nt0 = wv * 2;
  for (int kg = 0; kg < 4; kg++) {
    bf16x8 a[4];
#pragma unroll
    for (int kk = 0; kk < 4; kk++)
      a[kk] = *(const bf16x8*)&hs[ln][(kg * 4 + kk) * 32 + koff];
    bf16x8 b[2][4];
#pragma unroll
    for (int nt = 0; nt < 2; nt++)
#pragma unroll
      for (int kk = 0; kk < 4; kk++)
        b[nt][kk] = *(const bf16x8*)&W2F[(size_t)(((nt0 + nt) * 16 + kg * 4 + kk) * 64 + lane) * 8];
#pragma unroll
    for (int kk = 0; kk < 4; kk++)
#pragma unroll
      for (int nt = 0; nt < 2; nt++)
        acc2[nt] = __builtin_amdgcn_mfma_f32_16x16x32_bf16(a[kk], b[nt][kk], acc2[nt], 0, 0, 0);
  }
  __syncthreads();
#pragma unroll
  for (int nt = 0; nt < 2; nt++) {
    const int col = (nt0 + nt) * 16 + ln;
    const float bias = b2[col];
#pragma unroll
    for (int r = 0; r < 4; r++)
      ys[(quad * 4 + r) * 132 + col] = acc2[nt][r] + bias;
  }
  __syncthreads();
  float2 gg = *(const float2*)&g2[2 * lane];
  float2 bbe = *(const float2*)&be2[2 * lane];
#pragma unroll
  for (int rr = 0; rr < 4; rr++) {
    const int r = wv * 4 + rr;
    const int row = row0 + r;
    float2 xr = *(const float2*)&out[(size_t)row * ED + 2 * lane];
    float vx = ys[r * 132 + 2 * lane] + xr.x;
    float vy = ys[r * 132 + 2 * lane + 1] + xr.y;
    float mean = wave_sum(vx + vy) * (1.f / ED);
    float dx = vx - mean, dy = vy - mean;
    float var = wave_sum(dx * dx + dy * dy) * (1.f / ED);
    float rstd = rsqrtf(var + 1e-5f);
    float2 o = make_float2(dx * rstd * gg.x + bbe.x, dy * rstd * gg.y + bbe.y);
    *(float2*)&out[(size_t)row * ED + 2 * lane] = o;
  }
}

extern "C" void kernel_launch(void* const* d_in, const int* in_sizes, int n_in,
                              void* d_out, int out_size, void* d_ws, size_t ws_size,
                              hipStream_t stream) {
  const float* x = (const float*)d_in[0];
  const int* ei = (const int*)d_in[1];
  const float* W_qkv = (const float*)d_in[2];
  const float* b_qkv = (const float*)d_in[3];
  const float* W1 = (const float*)d_in[4];
  const float* b1 = (const float*)d_in[5];
  const float* W2 = (const float*)d_in[6];
  const float* b2 = (const float*)d_in[7];
  const float* g1 = (const float*)d_in[8];
  const float* be1 = (const float*)d_in[9];
  const float* g2 = (const float*)d_in[10];
  const float* be2 = (const float*)d_in[11];
  float* out = (float*)d_out;

  char* ws = (char*)d_ws;
  size_t off = 0;
  auto alloc = [&](size_t bytes) -> char* {
    char* p = ws + off;
    off = (off + bytes + 255) & ~(size_t)255;
    return p;
  };
  unsigned short* q = (unsigned short*)alloc(2 * (size_t)NN * ED);
  unsigned short* k = (unsigned short*)alloc(2 * (size_t)NN * ED);
  unsigned short* v = (unsigned short*)alloc(2 * (size_t)NN * ED);
  unsigned short* WqkvF = (unsigned short*)alloc(2 * 24 * 4 * 64 * 8);
  unsigned short* W1F = (unsigned short*)alloc(2 * 32 * 4 * 64 * 8);
  unsigned short* W2F = (unsigned short*)alloc(2 * 8 * 16 * 64 * 8);
  int* deg = (int*)alloc(sizeof(int) * NN);
  int* cursor = (int*)alloc(sizeof(int) * NN);
  int* row_start = (int*)alloc(sizeof(int) * (NN + 1));
  int* colidx = (int*)alloc(sizeof(int) * NE);
  int* blocksum = (int*)alloc(sizeof(int) * SCAN_BLOCKS);

  k_prep<<<256, 256, 0, stream>>>(W_qkv, W1, W2, WqkvF, W1F, W2F, deg);
  k_qkv_hist<<<QKV_BLOCKS + HIST_BLOCKS, 256, 0, stream>>>(x, WqkvF, b_qkv, q, k, v, ei, deg);
  k_scan1<<<SCAN_BLOCKS, 256, 0, stream>>>(deg, blocksum);
  k_scan3<<<SCAN_BLOCKS, 256, 0, stream>>>(deg, blocksum, row_start, cursor);
  k_scatter<<<HIST_BLOCKS, 256, 0, stream>>>(ei, ei + NE, cursor, colidx);
  k_attn_ln1<<<NN / 4, 256, 0, stream>>>(q, k, v, x, row_start, colidx, g1, be1, out);
  k_ffn_ln2<<<NN / 16, 256, 0, stream>>>(out, W1F, b1, W2F, b2, g2, be2, out);
}

// Round 4
// 294.952 us; speedup vs baseline: 1.1698x; 1.0159x over previous
//
#include <hip/hip_runtime.h>
#include <math.h>

#define NN 50000
#define NE 800000
#define ED 128
#define FD 512
#define QKV_BLOCKS (NN / 16)                // 3125
#define HIST_BLOCKS ((NE / 4 + 255) / 256)  // 782
#define SCAN_BLOCKS ((NN + 255) / 256)      // 196

typedef __attribute__((ext_vector_type(8))) short bf16x8;
typedef __attribute__((ext_vector_type(4))) float f32x4;
typedef _Float16 half2_t __attribute__((ext_vector_type(2)));

static __device__ __forceinline__ float wave_sum(float x) {
#pragma unroll
  for (int off = 32; off > 0; off >>= 1) x += __shfl_xor(x, off, 64);
  return x;
}

static __device__ __forceinline__ int wave_sum_i(int x) {
#pragma unroll
  for (int off = 32; off > 0; off >>= 1) x += __shfl_xor(x, off, 64);
  return x;
}

static __device__ __forceinline__ unsigned short f2bf(float f) {
  union { float f; unsigned u; } c; c.f = f;
  unsigned r = c.u + 0x7fffu + ((c.u >> 16) & 1u);
  return (unsigned short)(r >> 16);
}

static __device__ __forceinline__ unsigned short f2h(float f) {
  union { _Float16 h; unsigned short u; } c; c.h = (_Float16)f;
  return c.u;
}

static __device__ __forceinline__ half2_t u2h2(unsigned u) {
  union { unsigned u; half2_t h; } c; c.u = u;
  return c.h;
}

#if __has_builtin(__builtin_amdgcn_fdot2)
#define FDOT2(a, b, c) __builtin_amdgcn_fdot2((a), (b), (c), false)
#else
static __device__ __forceinline__ float FDOT2(half2_t a, half2_t b, float c) {
  return (float)a[0] * (float)b[0] + (float)a[1] * (float)b[1] + c;
}
#endif

// ---- one-time weight swizzle to fragment-major bf16 + deg zero ----
__global__ void k_prep(const float* __restrict__ Wqkv, const float* __restrict__ W1,
                       const float* __restrict__ W2, unsigned short* __restrict__ WqkvF,
                       unsigned short* __restrict__ W1F, unsigned short* __restrict__ W2F,
                       int* __restrict__ deg) {
  int idx = blockIdx.x * 256 + threadIdx.x;  // 65536 threads
  if (idx < NN) deg[idx] = 0;
  if (idx < 49152) {  // WqkvF: t<24, kb<4
    int j = idx & 7, l = (idx >> 3) & 63, kb = (idx >> 9) & 3, t = idx >> 11;
    int k = kb * 32 + (l >> 4) * 8 + j, n = t * 16 + (l & 15);
    WqkvF[idx] = f2bf(Wqkv[k * 384 + n]);
  }
  {  // W1F: t<32, kb<4
    int j = idx & 7, l = (idx >> 3) & 63, kb = (idx >> 9) & 3, t = idx >> 11;
    int k = kb * 32 + (l >> 4) * 8 + j, n = t * 16 + (l & 15);
    W1F[idx] = f2bf(W1[k * 512 + n]);
  }
  {  // W2F: t<8, kb<16
    int j = idx & 7, l = (idx >> 3) & 63, kb = (idx >> 9) & 15, t = idx >> 13;
    int k = kb * 32 + (l >> 4) * 8 + j, n = t * 16 + (l & 15);
    W2F[idx] = f2bf(W2[k * 128 + n]);
  }
}

// ---- fused: QKV GEMM + histogram ----
// q stored f16 pre-scaled by 128^-0.5; k/v stored f16 interleaved per node:
// kv[c*256 + d] = K_d, kv[c*256 + 128 + d] = V_d  (one 512B region per edge).
__global__ __launch_bounds__(256) void k_qkv_hist(
    const float* __restrict__ X, const unsigned short* __restrict__ WqkvF,
    const float* __restrict__ B, unsigned short* __restrict__ q,
    unsigned short* __restrict__ kv, const int* __restrict__ src,
    int* __restrict__ deg) {
  __shared__ unsigned short xs[16][136];
  const int tid = threadIdx.x;
  if (blockIdx.x >= QKV_BLOCKS) {
    const int e0 = ((blockIdx.x - QKV_BLOCKS) * 256 + tid) * 4;
    if (e0 < NE) {
      int4 s4 = *(const int4*)&src[e0];
      atomicAdd(&deg[s4.x], 1);
      atomicAdd(&deg[s4.y], 1);
      atomicAdd(&deg[s4.z], 1);
      atomicAdd(&deg[s4.w], 1);
    }
    return;
  }
  const int row0 = blockIdx.x * 16;
  for (int idx = tid; idx < 512; idx += 256) {
    int r = idx >> 5, c4 = (idx & 31) << 2;
    float4 val = *(const float4*)&X[(size_t)(row0 + r) * ED + c4];
    xs[r][c4] = f2bf(val.x); xs[r][c4 + 1] = f2bf(val.y);
    xs[r][c4 + 2] = f2bf(val.z); xs[r][c4 + 3] = f2bf(val.w);
  }
  __syncthreads();
  const int wv = tid >> 6, lane = tid & 63;
  const int ln = lane & 15, quad = lane >> 4;
  const int koff = quad * 8;
  bf16x8 a[4];
#pragma unroll
  for (int kb = 0; kb < 4; kb++) a[kb] = *(const bf16x8*)&xs[ln][kb * 32 + koff];
  for (int g = 0; g < 3; g++) {
    const int t0 = wv * 6 + g * 2;
    bf16x8 b[2][4];
#pragma unroll
    for (int j = 0; j < 2; j++)
#pragma unroll
      for (int kb = 0; kb < 4; kb++)
        b[j][kb] = *(const bf16x8*)&WqkvF[(size_t)(((t0 + j) * 4 + kb) * 64 + lane) * 8];
    f32x4 acc[2];
#pragma unroll
    for (int j = 0; j < 2; j++) acc[j] = (f32x4){0.f, 0.f, 0.f, 0.f};
#pragma unroll
    for (int kb = 0; kb < 4; kb++)
#pragma unroll
      for (int j = 0; j < 2; j++)
        acc[j] = __builtin_amdgcn_mfma_f32_16x16x32_bf16(a[kb], b[j][kb], acc[j], 0, 0, 0);
#pragma unroll
    for (int j = 0; j < 2; j++) {
      const int col = (t0 + j) * 16 + ln;
      const float bias = B[col];
      if (col < 128) {
#pragma unroll
        for (int r = 0; r < 4; r++)
          q[(size_t)(row0 + quad * 4 + r) * ED + col] =
              f2h((acc[j][r] + bias) * 0.08838834764831845f);  // 128^-0.5
      } else {
        // both K (col 128..255) and V (col 256..383) land at kv[row*256 + col-128]
#pragma unroll
        for (int r = 0; r < 4; r++)
          kv[(size_t)(row0 + quad * 4 + r) * 256 + (col - 128)] = f2h(acc[j][r] + bias);
      }
    }
  }
}

// ---- two-phase parallel scan ----
__global__ __launch_bounds__(256) void k_scan1(const int* __restrict__ deg,
                                               int* __restrict__ blocksum) {
  const int tid = threadIdx.x;
  const int i = blockIdx.x * 256 + tid;
  int d = (i < NN) ? deg[i] : 0;
  int w = wave_sum_i(d);
  __shared__ int ws[4];
  if ((tid & 63) == 0) ws[tid >> 6] = w;
  __syncthreads();
  if (tid == 0) blocksum[blockIdx.x] = ws[0] + ws[1] + ws[2] + ws[3];
}

__global__ __launch_bounds__(256) void k_scan3(const int* __restrict__ deg,
                                               const int* __restrict__ blocksum,
                                               int* __restrict__ row_start,
                                               int* __restrict__ cursor) {
  __shared__ int bs[256];
  __shared__ int s[256];
  const int t = threadIdx.x;
  int bsv = (t < SCAN_BLOCKS) ? blocksum[t] : 0;
  bs[t] = bsv;
  __syncthreads();
  for (int off = 1; off < 256; off <<= 1) {
    int add = (t >= off) ? bs[t - off] : 0;
    __syncthreads();
    bs[t] += add;
    __syncthreads();
  }
  const int blockpre = (blockIdx.x > 0) ? bs[blockIdx.x - 1] : 0;
  const int i = blockIdx.x * 256 + t;
  int d = (i < NN) ? deg[i] : 0;
  s[t] = d;
  __syncthreads();
  for (int off = 1; off < 256; off <<= 1) {
    int add = (t >= off) ? s[t - off] : 0;
    __syncthreads();
    s[t] += add;
    __syncthreads();
  }
  const int pre = blockpre + s[t] - d;
  if (i < NN) {
    row_start[i] = pre;
    cursor[i] = pre;
  }
  if (i == NN) row_start[NN] = pre;
}

__global__ void k_scatter(const int* __restrict__ src, const int* __restrict__ dst,
                          int* __restrict__ cursor, int* __restrict__ colidx) {
  const int e0 = (blockIdx.x * 256 + threadIdx.x) * 4;
  if (e0 < NE) {
    int4 s4 = *(const int4*)&src[e0];
    int4 d4 = *(const int4*)&dst[e0];
    colidx[atomicAdd(&cursor[s4.x], 1)] = d4.x;
    colidx[atomicAdd(&cursor[s4.y], 1)] = d4.y;
    colidx[atomicAdd(&cursor[s4.z], 1)] = d4.z;
    colidx[atomicAdd(&cursor[s4.w], 1)] = d4.w;
  }
}

// ---- attention chunk, f16 packed-math edition ----
// Issue-bound theory: round-0 vs round-2 showed time invariant under 4x
// load-ILP change at ~55% VALUBusy -> the instruction stream is the limiter.
// Cuts: (1) fdot2 (v_dot2_f32_f16) replaces 8 unpack + 8 fma for the dot;
// (2) packed v_pk_fma_f16 replaces 8 unpack + 8 fma for the V accumulate;
// (3) tail iterations with all 4 groups inactive are skipped entirely
//     (was ~32% of all iterations at mean degree 16);
// (4) one address per edge: K and V in one 512B kv row, V at +256B imm offset.
template <bool FULL>
static __device__ __forceinline__ void attn_chunk(
    int base, int cnt, int grp, int gl, int lane, const half2_t* qh,
    const unsigned short* __restrict__ kv, const int* __restrict__ colidx,
    float& l, half2_t* axh) {
  const int C = FULL ? 16 : cnt;
  int colreg = 0;
  if (lane < C) colreg = colidx[base + lane];
  const int itmax = FULL ? 4 : ((C + 3) >> 2);
#pragma unroll(FULL ? 4 : 1)
  for (int it = 0; it < itmax; it++) {
    const int t = it * 4 + grp;
    const bool act = FULL || t < C;
    // inactive lanes re-load slot 0's row (valid, cache-hot, masked by e=0)
    const int cc = __shfl(colreg, act ? t : 0, 64);
    const unsigned short* row = &kv[(size_t)cc * 256 + gl * 8];
    uint4 kw = *(const uint4*)row;
    uint4 vw = *(const uint4*)(row + 128);  // imm offset:256 off same base
    float dot = FDOT2(qh[0], u2h2(kw.x), 0.f);
    dot = FDOT2(qh[1], u2h2(kw.y), dot);
    dot = FDOT2(qh[2], u2h2(kw.z), dot);
    dot = FDOT2(qh[3], u2h2(kw.w), dot);
    dot += __shfl_xor(dot, 1, 64);
    dot += __shfl_xor(dot, 2, 64);
    dot += __shfl_xor(dot, 4, 64);
    dot += __shfl_xor(dot, 8, 64);
    const float e = act ? __expf(dot) : 0.f;  // q pre-scaled by 128^-0.5
    l += e;
    const half2_t e2 = {(_Float16)e, (_Float16)e};
    axh[0] += e2 * u2h2(vw.x);
    axh[1] += e2 * u2h2(vw.y);
    axh[2] += e2 * u2h2(vw.z);
    axh[3] += e2 * u2h2(vw.w);
  }
}

__global__ __launch_bounds__(256) void k_attn_ln1(
    const unsigned short* __restrict__ q, const unsigned short* __restrict__ kv,
    const float* __restrict__ x, const int* __restrict__ row_start,
    const int* __restrict__ colidx, const float* __restrict__ g1,
    const float* __restrict__ be1, float* __restrict__ out) {
  const int wv = threadIdx.x >> 6;
  const int lane = threadIdx.x & 63;
  const int grp = lane >> 4, gl = lane & 15;
  const int node = blockIdx.x * 4 + wv;  // NN % 4 == 0

  half2_t qh[4];
  {
    uint4 qw = *(const uint4*)&q[(size_t)node * ED + gl * 8];
    qh[0] = u2h2(qw.x); qh[1] = u2h2(qw.y);
    qh[2] = u2h2(qw.z); qh[3] = u2h2(qw.w);
  }
  const int r0 = row_start[node], r1 = row_start[node + 1];
  float l = 0.f;
  half2_t axh[4] = {};
  int base = r0;
  for (; base + 16 <= r1; base += 16)
    attn_chunk<true>(base, 16, grp, gl, lane, qh, kv, colidx, l, axh);
  if (base < r1)
    attn_chunk<false>(base, r1 - base, grp, gl, lane, qh, kv, colidx, l, axh);

  // cross-group reduction: groups hold disjoint edge subsets (packed halves)
#pragma unroll
  for (int j = 0; j < 4; j++) {
    union { half2_t h; int i; } c;
    union { int i; half2_t h; } d;
    c.h = axh[j]; d.i = __shfl_xor(c.i, 16, 64); axh[j] += d.h;
    c.h = axh[j]; d.i = __shfl_xor(c.i, 32, 64); axh[j] += d.h;
  }
  l += __shfl_xor(l, 16, 64);
  l += __shfl_xor(l, 32, 64);

  const float inv = (r1 > r0) ? 1.0f / l : 0.f;
  // this lane outputs dims d0, d0+1 (dims partitioned uniquely over 64 lanes)
  const int d0 = gl * 8 + grp * 2;
  const half2_t s = (grp == 0) ? axh[0] : (grp == 1) ? axh[1] : (grp == 2) ? axh[2] : axh[3];
  const float sx = (float)s[0], sy = (float)s[1];
  float2 xv = *(const float2*)&x[(size_t)node * ED + d0];
  float vx = xv.x + sx * inv;
  float vy = xv.y + sy * inv;
  float mean = wave_sum(vx + vy) * (1.f / ED);
  float dx = vx - mean, dy = vy - mean;
  float var = wave_sum(dx * dx + dy * dy) * (1.f / ED);
  float rstd = rsqrtf(var + 1e-5f);
  float2 gg = *(const float2*)&g1[d0];
  float2 bb = *(const float2*)&be1[d0];
  float2 o = make_float2(dx * rstd * gg.x + bb.x, dy * rstd * gg.y + bb.y);
  *(float2*)&out[(size_t)node * ED + d0] = o;
}

// ---- FFN via MFMA: 16 rows/block + residual + LN2, in-place on out ----
__global__ __launch_bounds__(256) void k_ffn_ln2(
    const float* __restrict__ x1, const unsigned short* __restrict__ W1F,
    const float* __restrict__ b1, const unsigned short* __restrict__ W2F,
    const float* __restrict__ b2, const float* __restrict__ g2,
    const float* __restrict__ be2, float* __restrict__ out) {
  __shared__ unsigned short xs[16][136];
  __shared__ unsigned short hs[16][520];  // later aliased ys f32[16][132]
  float* ys = (float*)&hs[0][0];
  const int row0 = blockIdx.x * 16;
  const int tid = threadIdx.x;
  for (int idx = tid; idx < 512; idx += 256) {
    int r = idx >> 5, c4 = (idx & 31) << 2;
    float4 val = *(const float4*)&x1[(size_t)(row0 + r) * ED + c4];
    xs[r][c4] = f2bf(val.x); xs[r][c4 + 1] = f2bf(val.y);
    xs[r][c4 + 2] = f2bf(val.z); xs[r][c4 + 3] = f2bf(val.w);
  }
  __syncthreads();
  const int wv = tid >> 6, lane = tid & 63;
  const int ln = lane & 15, quad = lane >> 4;
  const int koff = quad * 8;
  bf16x8 a1[4];
#pragma unroll
  for (int kb = 0; kb < 4; kb++) a1[kb] = *(const bf16x8*)&xs[ln][kb * 32 + koff];
  for (int g = 0; g < 4; g++) {
    const int t0 = wv * 8 + g * 2;
    bf16x8 b[2][4];
#pragma unroll
    for (int j = 0; j < 2; j++)
#pragma unroll
      for (int kb = 0; kb < 4; kb++)
        b[j][kb] = *(const bf16x8*)&W1F[(size_t)(((t0 + j) * 4 + kb) * 64 + lane) * 8];
    f32x4 acc[2];
#pragma unroll
    for (int j = 0; j < 2; j++) acc[j] = (f32x4){0.f, 0.f, 0.f, 0.f};
#pragma unroll
    for (int kb = 0; kb < 4; kb++)
#pragma unroll
      for (int j = 0; j < 2; j++)
        acc[j] = __builtin_amdgcn_mfma_f32_16x16x32_bf16(a1[kb], b[j][kb], acc[j], 0, 0, 0);
#pragma unroll
    for (int j = 0; j < 2; j++) {
      const int col = (t0 + j) * 16 + ln;
      const float bias = b1[col];
#pragma unroll
      for (int r = 0; r < 4; r++)
        hs[quad * 4 + r][col] = f2bf(fmaxf(acc[j][r] + bias, 0.f));
    }
  }
  __syncthreads();
  f32x4 acc2[2];
  acc2[0] = (f32x4){0.f, 0.f, 0.f, 0.f};
  acc2[1] = (f32x4){0.f, 0.f, 0.f, 0.f};
  const int nt0 = wv * 2;
  for (int kg = 0; kg < 4; kg++) {
    bf16x8 a[4];
#pragma unroll
    for (int kk = 0; kk < 4; kk++)
      a[kk] = *(const bf16x8*)&hs[ln][(kg * 4 + kk) * 32 + koff];
    bf16x8 b[2][4];
#pragma unroll
    for (int nt = 0; nt < 2; nt++)
#pragma unroll
      for (int kk = 0; kk < 4; kk++)
        b[nt][kk] = *(const bf16x8*)&W2F[(size_t)(((nt0 + nt) * 16 + kg * 4 + kk) * 64 + lane) * 8];
#pragma unroll
    for (int kk = 0; kk < 4; kk++)
#pragma unroll
      for (int nt = 0; nt < 2; nt++)
        acc2[nt] = __builtin_amdgcn_mfma_f32_16x16x32_bf16(a[kk], b[nt][kk], acc2[nt], 0, 0, 0);
  }
  __syncthreads();
#pragma unroll
  for (int nt = 0; nt < 2; nt++) {
    const int col = (nt0 + nt) * 16 + ln;
    const float bias = b2[col];
#pragma unroll
    for (int r = 0; r < 4; r++)
      ys[(quad * 4 + r) * 132 + col] = acc2[nt][r] + bias;
  }
  __syncthreads();
  float2 gg = *(const float2*)&g2[2 * lane];
  float2 bbe = *(const float2*)&be2[2 * lane];
#pragma unroll
  for (int rr = 0; rr < 4; rr++) {
    const int r = wv * 4 + rr;
    const int row = row0 + r;
    float2 xr = *(const float2*)&out[(size_t)row * ED + 2 * lane];
    float vx = ys[r * 132 + 2 * lane] + xr.x;
    float vy = ys[r * 132 + 2 * lane + 1] + xr.y;
    float mean = wave_sum(vx + vy) * (1.f / ED);
    float dx = vx - mean, dy = vy - mean;
    float var = wave_sum(dx * dx + dy * dy) * (1.f / ED);
    float rstd = rsqrtf(var + 1e-5f);
    float2 o = make_float2(dx * rstd * gg.x + bbe.x, dy * rstd * gg.y + bbe.y);
    *(float2*)&out[(size_t)row * ED + 2 * lane] = o;
  }
}

extern "C" void kernel_launch(void* const* d_in, const int* in_sizes, int n_in,
                              void* d_out, int out_size, void* d_ws, size_t ws_size,
                              hipStream_t stream) {
  const float* x = (const float*)d_in[0];
  const int* ei = (const int*)d_in[1];
  const float* W_qkv = (const float*)d_in[2];
  const float* b_qkv = (const float*)d_in[3];
  const float* W1 = (const float*)d_in[4];
  const float* b1 = (const float*)d_in[5];
  const float* W2 = (const float*)d_in[6];
  const float* b2 = (const float*)d_in[7];
  const float* g1 = (const float*)d_in[8];
  const float* be1 = (const float*)d_in[9];
  const float* g2 = (const float*)d_in[10];
  const float* be2 = (const float*)d_in[11];
  float* out = (float*)d_out;

  char* ws = (char*)d_ws;
  size_t off = 0;
  auto alloc = [&](size_t bytes) -> char* {
    char* p = ws + off;
    off = (off + bytes + 255) & ~(size_t)255;
    return p;
  };
  unsigned short* q = (unsigned short*)alloc(2 * (size_t)NN * ED);
  unsigned short* kv = (unsigned short*)alloc(2 * (size_t)NN * 256);
  unsigned short* WqkvF = (unsigned short*)alloc(2 * 24 * 4 * 64 * 8);
  unsigned short* W1F = (unsigned short*)alloc(2 * 32 * 4 * 64 * 8);
  unsigned short* W2F = (unsigned short*)alloc(2 * 8 * 16 * 64 * 8);
  int* deg = (int*)alloc(sizeof(int) * NN);
  int* cursor = (int*)alloc(sizeof(int) * NN);
  int* row_start = (int*)alloc(sizeof(int) * (NN + 1));
  int* colidx = (int*)alloc(sizeof(int) * NE);
  int* blocksum = (int*)alloc(sizeof(int) * SCAN_BLOCKS);

  k_prep<<<256, 256, 0, stream>>>(W_qkv, W1, W2, WqkvF, W1F, W2F, deg);
  k_qkv_hist<<<QKV_BLOCKS + HIST_BLOCKS, 256, 0, stream>>>(x, WqkvF, b_qkv, q, kv, ei, deg);
  k_scan1<<<SCAN_BLOCKS, 256, 0, stream>>>(deg, blocksum);
  k_scan3<<<SCAN_BLOCKS, 256, 0, stream>>>(deg, blocksum, row_start, cursor);
  k_scatter<<<HIST_BLOCKS, 256, 0, stream>>>(ei, ei + NE, cursor, colidx);
  k_attn_ln1<<<NN / 4, 256, 0, stream>>>(q, kv, x, row_start, colidx, g1, be1, out);
  k_ffn_ln2<<<NN / 16, 256, 0, stream>>>(out, W1F, b1, W2F, b2, g2, be2, out);
}